// Round 1
// baseline (490.092 us; speedup 1.0000x reference)
//
#include <hip/hip_runtime.h>
#include <hip/hip_bf16.h>
#include <math.h>

#define NN      6144
#define IN_DIM  512
#define CH      4
#define CDIM    64
#define NODE    (CH * CDIM)      // 256 floats per node
#define ROWS    16               // rows per projection block
#define MAXD    96               // max degree slot (mean ~31, ~12 sigma margin)

// ---------------------------------------------------------------------------
// Kernel 1: per-channel projection + bias + row L2-norm.
// Output layout: feats[n][k][c]  (node-major, 1 KB contiguous per node)
// ---------------------------------------------------------------------------
__global__ __launch_bounds__(256) void proj_kernel(
    const float* __restrict__ feat,   // [N, IN_DIM]
    const float* __restrict__ W,      // [CH, IN_DIM, CDIM]
    const float* __restrict__ bias,   // [CH, 1, CDIM]
    float* __restrict__ out)          // [N, CDIM, CH]
{
    __shared__ float lds[ROWS * IN_DIM];  // 32 KB
    const int t    = threadIdx.x;
    const int row0 = blockIdx.x * ROWS;

    // stage 16 feature rows into LDS (coalesced float4)
    const float4* src  = (const float4*)(feat + (size_t)row0 * IN_DIM);
    float4*       dst4 = (float4*)lds;
    for (int i = t; i < ROWS * IN_DIM / 4; i += 256) dst4[i] = src[i];
    __syncthreads();

    const int c = t >> 6;   // wave index == channel
    const int k = t & 63;   // lane == output dim

    float acc[ROWS];
#pragma unroll
    for (int r = 0; r < ROWS; ++r) acc[r] = 0.0f;

    const float* Wc = W + (size_t)c * IN_DIM * CDIM + k;  // stride CDIM per d
    for (int d = 0; d < IN_DIM; d += 4) {
        const float w0 = Wc[(d + 0) * CDIM];
        const float w1 = Wc[(d + 1) * CDIM];
        const float w2 = Wc[(d + 2) * CDIM];
        const float w3 = Wc[(d + 3) * CDIM];
#pragma unroll
        for (int r = 0; r < ROWS; ++r) {
            float4 f = *(const float4*)&lds[r * IN_DIM + d];  // broadcast b128
            acc[r] = fmaf(f.x, w0, fmaf(f.y, w1, fmaf(f.z, w2, fmaf(f.w, w3, acc[r]))));
        }
    }

    const float bv = bias[c * CDIM + k];
#pragma unroll
    for (int r = 0; r < ROWS; ++r) acc[r] += bv;

    // per-(row, channel) L2 norm over the 64 lanes (k dimension)
    float ss[ROWS];
#pragma unroll
    for (int r = 0; r < ROWS; ++r) ss[r] = acc[r] * acc[r];
#pragma unroll
    for (int off = 32; off >= 1; off >>= 1) {
#pragma unroll
        for (int r = 0; r < ROWS; ++r) ss[r] += __shfl_xor(ss[r], off, 64);
    }
#pragma unroll
    for (int r = 0; r < ROWS; ++r) {
        const float rn = 1.0f / fmaxf(sqrtf(ss[r]), 1e-12f);
        out[(size_t)(row0 + r) * NODE + k * CH + c] = acc[r] * rn;
    }
}

// ---------------------------------------------------------------------------
// Kernel 2: dense adj row -> fixed-width neighbor list (ELL). One block/row.
// ---------------------------------------------------------------------------
__global__ __launch_bounds__(256) void ell_kernel(
    const int* __restrict__ adj,   // [N, N] 0/1
    int* __restrict__ deg,         // [N]
    int* __restrict__ cols)        // [N, MAXD]
{
    __shared__ int cnt;
    const int n = blockIdx.x;
    if (threadIdx.x == 0) cnt = 0;
    __syncthreads();

    const int4* row = (const int4*)(adj + (size_t)n * NN);
    int* rowcols = cols + (size_t)n * MAXD;
    for (int i = threadIdx.x; i < NN / 4; i += 256) {
        const int4 v = row[i];
        const int base = i * 4;
        if (v.x) { int p = atomicAdd(&cnt, 1); if (p < MAXD) rowcols[p] = base + 0; }
        if (v.y) { int p = atomicAdd(&cnt, 1); if (p < MAXD) rowcols[p] = base + 1; }
        if (v.z) { int p = atomicAdd(&cnt, 1); if (p < MAXD) rowcols[p] = base + 2; }
        if (v.w) { int p = atomicAdd(&cnt, 1); if (p < MAXD) rowcols[p] = base + 3; }
    }
    __syncthreads();
    if (threadIdx.x == 0) deg[n] = min(cnt, MAXD);
}

// ---------------------------------------------------------------------------
// Kernel 3: one propagation iteration. One wave per row.
// lane k holds float4 over channels: fin[n][k][0..3]
// ---------------------------------------------------------------------------
__global__ __launch_bounds__(256) void iter_kernel(
    const float* __restrict__ fin,   // [N, CDIM, CH]
    float* __restrict__ fout,        // [N, CDIM, CH]
    const int* __restrict__ deg,
    const int* __restrict__ cols)
{
    const int wave = threadIdx.x >> 6;
    const int lane = threadIdx.x & 63;
    const int n = blockIdx.x * 4 + wave;

    const float4* fin4 = (const float4*)fin;
    const float4 q = fin4[(size_t)n * CDIM + lane];
    float4 acc = q;  // feats + agg starts from feats

    const int d = deg[n];
    const int* cl = cols + (size_t)n * MAXD;

    for (int i = 0; i < d; ++i) {
        const int m = cl[i];
        const float4 f = fin4[(size_t)m * CDIM + lane];

        // 4 channel dot products, reduced across the 64 lanes
        float s0 = q.x * f.x, s1 = q.y * f.y, s2 = q.z * f.z, s3 = q.w * f.w;
#pragma unroll
        for (int off = 32; off >= 1; off >>= 1) {
            s0 += __shfl_xor(s0, off, 64);
            s1 += __shfl_xor(s1, off, 64);
            s2 += __shfl_xor(s2, off, 64);
            s3 += __shfl_xor(s3, off, 64);
        }
        // softmax across the 4 channels (BETA == 1)
        const float mx = fmaxf(fmaxf(s0, s1), fmaxf(s2, s3));
        const float e0 = __expf(s0 - mx), e1 = __expf(s1 - mx);
        const float e2 = __expf(s2 - mx), e3 = __expf(s3 - mx);
        const float rs = 1.0f / (e0 + e1 + e2 + e3);
        acc.x = fmaf(e0 * rs, f.x, acc.x);
        acc.y = fmaf(e1 * rs, f.y, acc.y);
        acc.z = fmaf(e2 * rs, f.z, acc.z);
        acc.w = fmaf(e3 * rs, f.w, acc.w);
    }

    // per-channel L2 norm over k (64 lanes)
    float t0 = acc.x * acc.x, t1 = acc.y * acc.y;
    float t2 = acc.z * acc.z, t3 = acc.w * acc.w;
#pragma unroll
    for (int off = 32; off >= 1; off >>= 1) {
        t0 += __shfl_xor(t0, off, 64);
        t1 += __shfl_xor(t1, off, 64);
        t2 += __shfl_xor(t2, off, 64);
        t3 += __shfl_xor(t3, off, 64);
    }
    acc.x *= 1.0f / fmaxf(sqrtf(t0), 1e-12f);
    acc.y *= 1.0f / fmaxf(sqrtf(t1), 1e-12f);
    acc.z *= 1.0f / fmaxf(sqrtf(t2), 1e-12f);
    acc.w *= 1.0f / fmaxf(sqrtf(t3), 1e-12f);

    float4* fo4 = (float4*)fout;
    fo4[(size_t)n * CDIM + lane] = acc;
}

// ---------------------------------------------------------------------------
// Kernel 4: [n][k][c] -> [n][c*64+k] final layout
// ---------------------------------------------------------------------------
__global__ __launch_bounds__(256) void out_kernel(
    const float* __restrict__ fin, float* __restrict__ out)
{
    const int idx = blockIdx.x * 256 + threadIdx.x;  // n*256 + c*64 + k
    const int n = idx >> 8;
    const int c = (idx >> 6) & 3;
    const int k = idx & 63;
    out[idx] = fin[(size_t)n * NODE + k * CH + c];
}

extern "C" void kernel_launch(void* const* d_in, const int* in_sizes, int n_in,
                              void* d_out, int out_size, void* d_ws, size_t ws_size,
                              hipStream_t stream) {
    const float* features = (const float*)d_in[0];   // [6144, 512]
    const int*   adj      = (const int*)d_in[1];     // [6144, 6144]
    const float* W        = (const float*)d_in[2];   // [4, 512, 64]
    const float* b        = (const float*)d_in[3];   // [4, 1, 64]
    float* out = (float*)d_out;                      // [6144, 256]

    // workspace carve-up (~15 MB total)
    float* featsA = (float*)d_ws;                    // N*NODE floats
    float* featsB = featsA + (size_t)NN * NODE;
    int*   deg    = (int*)(featsB + (size_t)NN * NODE);
    int*   cols   = deg + NN;                        // N*MAXD ints

    proj_kernel<<<NN / ROWS, 256, 0, stream>>>(features, W, b, featsA);
    ell_kernel<<<NN, 256, 0, stream>>>(adj, deg, cols);
    iter_kernel<<<NN / 4, 256, 0, stream>>>(featsA, featsB, deg, cols);
    iter_kernel<<<NN / 4, 256, 0, stream>>>(featsB, featsA, deg, cols);
    iter_kernel<<<NN / 4, 256, 0, stream>>>(featsA, featsB, deg, cols);
    out_kernel<<<NN, 256, 0, stream>>>(featsB, out);
}

// Round 2
// 453.466 us; speedup vs baseline: 1.0808x; 1.0808x over previous
//
#include <hip/hip_runtime.h>
#include <hip/hip_bf16.h>
#include <math.h>

#define NN      6144
#define IN_DIM  512
#define CH      4
#define CDIM    64
#define NODE    (CH * CDIM)      // 256 floats per node
#define PROWS   16               // rows per projection wave
#define MAXD    96               // max degree slot (mean ~31, ~12 sigma margin)

// ---------------------------------------------------------------------------
// Kernel 1: per-channel projection + bias + row L2-norm.
// One 64-thread block (1 wave) per (16-row chunk, channel). Feature-row
// addresses depend only on blockIdx + loop var -> wave-uniform -> scalar
// s_load path (no LDS at all). W reads are lane-coalesced 256B, L2-resident.
// Output layout: feats[n][c][k]  (node-major, 1 KB contiguous per node)
// ---------------------------------------------------------------------------
__global__ __launch_bounds__(64) void proj_kernel(
    const float* __restrict__ feat,   // [N, IN_DIM]
    const float* __restrict__ W,      // [CH, IN_DIM, CDIM]
    const float* __restrict__ bias,   // [CH, 1, CDIM]
    float* __restrict__ out)          // [N, CH, CDIM]
{
    const int k    = threadIdx.x;         // lane = output dim
    const int c    = blockIdx.x & 3;      // channel
    const int row0 = (blockIdx.x >> 2) * PROWS;

    float acc[PROWS];
#pragma unroll
    for (int r = 0; r < PROWS; ++r) acc[r] = 0.0f;

    const float* Wc = W + (size_t)c * IN_DIM * CDIM + k;  // stride CDIM per d
    for (int d = 0; d < IN_DIM; d += 4) {
        const float w0 = Wc[(d + 0) * CDIM];
        const float w1 = Wc[(d + 1) * CDIM];
        const float w2 = Wc[(d + 2) * CDIM];
        const float w3 = Wc[(d + 3) * CDIM];
#pragma unroll
        for (int r = 0; r < PROWS; ++r) {
            // wave-uniform address -> scalar load + SGPR broadcast
            const float4 f = *(const float4*)(feat + (size_t)(row0 + r) * IN_DIM + d);
            acc[r] = fmaf(f.x, w0, fmaf(f.y, w1, fmaf(f.z, w2, fmaf(f.w, w3, acc[r]))));
        }
    }

    const float bv = bias[c * CDIM + k];
#pragma unroll
    for (int r = 0; r < PROWS; ++r) acc[r] += bv;

    // per-(row, channel) L2 norm over the 64 lanes (k dimension)
    float ss[PROWS];
#pragma unroll
    for (int r = 0; r < PROWS; ++r) ss[r] = acc[r] * acc[r];
#pragma unroll
    for (int off = 32; off >= 1; off >>= 1) {
#pragma unroll
        for (int r = 0; r < PROWS; ++r) ss[r] += __shfl_xor(ss[r], off, 64);
    }
#pragma unroll
    for (int r = 0; r < PROWS; ++r) {
        const float rn = 1.0f / fmaxf(sqrtf(ss[r]), 1e-12f);
        out[(size_t)(row0 + r) * NODE + c * CDIM + k] = acc[r] * rn;
    }
}

// ---------------------------------------------------------------------------
// Kernel 2: dense adj row -> fixed-width neighbor list (ELL). One block/row.
// HBM-floor bound (151 MB stream). Fast-path skip for all-zero int4.
// ---------------------------------------------------------------------------
__global__ __launch_bounds__(256) void ell_kernel(
    const int* __restrict__ adj,   // [N, N] 0/1
    int* __restrict__ deg,         // [N]
    int* __restrict__ cols)        // [N, MAXD]
{
    __shared__ int cnt;
    const int n = blockIdx.x;
    if (threadIdx.x == 0) cnt = 0;
    __syncthreads();

    const int4* row = (const int4*)(adj + (size_t)n * NN);
    int* rowcols = cols + (size_t)n * MAXD;
    for (int i = threadIdx.x; i < NN / 4; i += 256) {
        const int4 v = row[i];
        if (v.x | v.y | v.z | v.w) {
            const int base = i * 4;
            if (v.x) { int p = atomicAdd(&cnt, 1); if (p < MAXD) rowcols[p] = base + 0; }
            if (v.y) { int p = atomicAdd(&cnt, 1); if (p < MAXD) rowcols[p] = base + 1; }
            if (v.z) { int p = atomicAdd(&cnt, 1); if (p < MAXD) rowcols[p] = base + 2; }
            if (v.w) { int p = atomicAdd(&cnt, 1); if (p < MAXD) rowcols[p] = base + 3; }
        }
    }
    __syncthreads();
    if (threadIdx.x == 0) deg[n] = min(cnt, MAXD);
}

// ---------------------------------------------------------------------------
// Kernel 3: one propagation iteration. One 64-thread block (1 wave) per row.
// Layout [n][c][k]: lane = c*16 + kq holds float4 of k = 4*kq..4*kq+3.
// Channel dot = 4-shfl segmented reduce over 16-lane group; cross-channel
// softmax via 3 exchange shuffles. Scores are unit-vector dots in [-1,1],
// so exp needs no max-subtraction. 7 DS ops/neighbor (was 24).
// ---------------------------------------------------------------------------
__global__ __launch_bounds__(64) void iter_kernel(
    const float* __restrict__ fin,   // [N, CH, CDIM]
    float* __restrict__ fout,        // [N, CH, CDIM]
    const int* __restrict__ deg,
    const int* __restrict__ cols)
{
    const int n    = blockIdx.x;     // wave-uniform
    const int lane = threadIdx.x;

    const float4* fin4 = (const float4*)fin;
    const float4 q = fin4[(size_t)n * 64 + lane];
    float4 acc = q;  // feats + agg starts from feats

    const int d = deg[n];                       // scalar load
    const int* cl = cols + (size_t)n * MAXD;    // scalar loads

    for (int i = 0; i < d; ++i) {
        const int m = cl[i];                    // wave-uniform
        const float4 f = fin4[(size_t)m * 64 + lane];

        // per-lane partial of this lane's channel dot (4 k-values)
        float p = fmaf(q.x, f.x, fmaf(q.y, f.y, fmaf(q.z, f.z, q.w * f.w)));
        // reduce within the 16-lane channel group
        p += __shfl_xor(p, 1, 64);
        p += __shfl_xor(p, 2, 64);
        p += __shfl_xor(p, 4, 64);
        p += __shfl_xor(p, 8, 64);
        // gather the other 3 channels' scores
        const float t1 = __shfl_xor(p, 16, 64);   // c^1
        const float t2 = __shfl_xor(p, 32, 64);   // c^2
        const float t3 = __shfl_xor(t1, 32, 64);  // c^3
        // softmax across channels; scores in [-1,1] -> no max needed
        const float e0 = __expf(p);
        const float es = e0 + __expf(t1) + __expf(t2) + __expf(t3);
        const float w  = e0 / es;
        acc.x = fmaf(w, f.x, acc.x);
        acc.y = fmaf(w, f.y, acc.y);
        acc.z = fmaf(w, f.z, acc.z);
        acc.w = fmaf(w, f.w, acc.w);
    }

    // per-channel L2 norm: reduce |acc|^2 over the 16-lane group
    float ss = fmaf(acc.x, acc.x, fmaf(acc.y, acc.y, fmaf(acc.z, acc.z, acc.w * acc.w)));
    ss += __shfl_xor(ss, 1, 64);
    ss += __shfl_xor(ss, 2, 64);
    ss += __shfl_xor(ss, 4, 64);
    ss += __shfl_xor(ss, 8, 64);
    const float rn = 1.0f / fmaxf(sqrtf(ss), 1e-12f);
    acc.x *= rn; acc.y *= rn; acc.z *= rn; acc.w *= rn;

    float4* fo4 = (float4*)fout;
    fo4[(size_t)n * 64 + lane] = acc;
}

extern "C" void kernel_launch(void* const* d_in, const int* in_sizes, int n_in,
                              void* d_out, int out_size, void* d_ws, size_t ws_size,
                              hipStream_t stream) {
    const float* features = (const float*)d_in[0];   // [6144, 512]
    const int*   adj      = (const int*)d_in[1];     // [6144, 6144]
    const float* W        = (const float*)d_in[2];   // [4, 512, 64]
    const float* b        = (const float*)d_in[3];   // [4, 1, 64]
    float* out = (float*)d_out;                      // [6144, 256] == [n][c][k] flat

    // workspace carve-up (~22 MB total)
    float* featsA = (float*)d_ws;                    // N*NODE floats
    float* featsB = featsA + (size_t)NN * NODE;
    int*   deg    = (int*)(featsB + (size_t)NN * NODE);
    int*   cols   = deg + NN;                        // N*MAXD ints

    proj_kernel<<<(NN / PROWS) * CH, 64, 0, stream>>>(features, W, b, featsA);
    ell_kernel<<<NN, 256, 0, stream>>>(adj, deg, cols);
    iter_kernel<<<NN, 64, 0, stream>>>(featsA, featsB, deg, cols);
    iter_kernel<<<NN, 64, 0, stream>>>(featsB, featsA, deg, cols);
    // final iteration writes d_out directly: [n][c][k] == [n][c*64+k]
    iter_kernel<<<NN, 64, 0, stream>>>(featsA, out, deg, cols);
}

// Round 3
// 341.213 us; speedup vs baseline: 1.4363x; 1.3290x over previous
//
#include <hip/hip_runtime.h>
#include <hip/hip_bf16.h>
#include <math.h>

#define NN      6144
#define IN_DIM  512
#define CH      4
#define CDIM    64
#define NODE    (CH * CDIM)      // 256 floats per node
#define PR      16               // rows per projection block
#define MAXD    96               // max degree slot (mean ~31, ~12 sigma margin)

// ---------------------------------------------------------------------------
// Kernel 1: projection as register-blocked fp32 GEMM + bias + L2 norm.
// 256 threads/block; 16 feature rows staged in LDS once (32 KB), reused by
// all 256 output cols. Thread (wave g, lane q) owns a 4x4 tile:
// rows row0+4g..+3, cols (c= q>>4, k0=(q&15)*4). Per K-step: 4 broadcast
// ds_read_b128 + 4 coalesced W dwordx4 + 64 v_fma -> FMA-issue-bound.
// Output layout: feats[n][c][k] (node-major 1 KB)
// ---------------------------------------------------------------------------
__global__ __launch_bounds__(256) void proj_kernel(
    const float* __restrict__ feat,   // [N, IN_DIM]
    const float* __restrict__ W,      // [CH, IN_DIM, CDIM]
    const float* __restrict__ bias,   // [CH, 1, CDIM]
    float* __restrict__ out)          // [N, CH, CDIM]
{
    __shared__ float lds[PR * IN_DIM];  // 32 KB
    const int t    = threadIdx.x;
    const int row0 = blockIdx.x * PR;

    // stage 16 rows, coalesced float4
    {
        const float4* src = (const float4*)(feat + (size_t)row0 * IN_DIM);
        float4* dst = (float4*)lds;
#pragma unroll
        for (int i = 0; i < (PR * IN_DIM / 4) / 256; ++i)
            dst[t + i * 256] = src[t + i * 256];
    }
    __syncthreads();

    const int g  = t >> 6;        // wave = row sub-group (4 rows)
    const int q  = t & 63;        // col quad id
    const int c  = q >> 4;        // channel
    const int k0 = (q & 15) * 4;  // col offset within channel

    float acc[4][4];
#pragma unroll
    for (int r = 0; r < 4; ++r)
#pragma unroll
        for (int j = 0; j < 4; ++j) acc[r][j] = 0.0f;

    const float* Wc   = W + (size_t)c * IN_DIM * CDIM + k0;
    const float* arow = lds + g * 4 * IN_DIM;

    for (int d = 0; d < IN_DIM; d += 4) {
        const float4 w0 = *(const float4*)(Wc + (size_t)(d + 0) * CDIM);
        const float4 w1 = *(const float4*)(Wc + (size_t)(d + 1) * CDIM);
        const float4 w2 = *(const float4*)(Wc + (size_t)(d + 2) * CDIM);
        const float4 w3 = *(const float4*)(Wc + (size_t)(d + 3) * CDIM);
#pragma unroll
        for (int r = 0; r < 4; ++r) {
            const float4 a = *(const float4*)(arow + r * IN_DIM + d);  // wave-uniform -> broadcast
            acc[r][0] = fmaf(a.x, w0.x, fmaf(a.y, w1.x, fmaf(a.z, w2.x, fmaf(a.w, w3.x, acc[r][0]))));
            acc[r][1] = fmaf(a.x, w0.y, fmaf(a.y, w1.y, fmaf(a.z, w2.y, fmaf(a.w, w3.y, acc[r][1]))));
            acc[r][2] = fmaf(a.x, w0.z, fmaf(a.y, w1.z, fmaf(a.z, w2.z, fmaf(a.w, w3.z, acc[r][2]))));
            acc[r][3] = fmaf(a.x, w0.w, fmaf(a.y, w1.w, fmaf(a.z, w2.w, fmaf(a.w, w3.w, acc[r][3]))));
        }
    }

    const float4 bv = *(const float4*)(bias + c * CDIM + k0);
#pragma unroll
    for (int r = 0; r < 4; ++r) {
        acc[r][0] += bv.x; acc[r][1] += bv.y; acc[r][2] += bv.z; acc[r][3] += bv.w;
    }

    // L2 norm per (row, channel): reduce over the 16 lanes of this channel
    float4 res[4];
#pragma unroll
    for (int r = 0; r < 4; ++r) {
        float ss = acc[r][0] * acc[r][0] + acc[r][1] * acc[r][1]
                 + acc[r][2] * acc[r][2] + acc[r][3] * acc[r][3];
        ss += __shfl_xor(ss, 1, 64);
        ss += __shfl_xor(ss, 2, 64);
        ss += __shfl_xor(ss, 4, 64);
        ss += __shfl_xor(ss, 8, 64);
        const float rn = 1.0f / fmaxf(sqrtf(ss), 1e-12f);
        res[r] = make_float4(acc[r][0] * rn, acc[r][1] * rn, acc[r][2] * rn, acc[r][3] * rn);
    }
#pragma unroll
    for (int r = 0; r < 4; ++r) {
        *(float4*)(out + (size_t)(row0 + g * 4 + r) * NODE + c * CDIM + k0) = res[r];
    }
}

// ---------------------------------------------------------------------------
// Kernel 2: dense adj row -> fixed-width neighbor list (ELL). One block/row.
// HBM-floor bound (151 MB stream). Fast-path skip for all-zero int4.
// ---------------------------------------------------------------------------
__global__ __launch_bounds__(256) void ell_kernel(
    const int* __restrict__ adj,   // [N, N] 0/1
    int* __restrict__ deg,         // [N]
    int* __restrict__ cols)        // [N, MAXD]
{
    __shared__ int cnt;
    const int n = blockIdx.x;
    if (threadIdx.x == 0) cnt = 0;
    __syncthreads();

    const int4* row = (const int4*)(adj + (size_t)n * NN);
    int* rowcols = cols + (size_t)n * MAXD;
    for (int i = threadIdx.x; i < NN / 4; i += 256) {
        const int4 v = row[i];
        if (v.x | v.y | v.z | v.w) {
            const int base = i * 4;
            if (v.x) { int p = atomicAdd(&cnt, 1); if (p < MAXD) rowcols[p] = base + 0; }
            if (v.y) { int p = atomicAdd(&cnt, 1); if (p < MAXD) rowcols[p] = base + 1; }
            if (v.z) { int p = atomicAdd(&cnt, 1); if (p < MAXD) rowcols[p] = base + 2; }
            if (v.w) { int p = atomicAdd(&cnt, 1); if (p < MAXD) rowcols[p] = base + 3; }
        }
    }
    __syncthreads();
    if (threadIdx.x == 0) deg[n] = min(cnt, MAXD);
}

// ---------------------------------------------------------------------------
// Kernel 3: one propagation iteration. One wave per row, 2-way neighbor
// unroll to overlap the gather->shfl-reduce->exp dependency chains.
// Layout [n][c][k]: lane = c*16 + kq holds float4 of k = 4*kq..4*kq+3.
// Scores are unit-vector dots in [-1,1] -> softmax needs no max shift.
// ---------------------------------------------------------------------------
__global__ __launch_bounds__(64) void iter_kernel(
    const float* __restrict__ fin,   // [N, CH, CDIM]
    float* __restrict__ fout,        // [N, CH, CDIM]
    const int* __restrict__ deg,
    const int* __restrict__ cols)
{
    const int n    = blockIdx.x;     // wave-uniform
    const int lane = threadIdx.x;

    const float4* fin4 = (const float4*)fin;
    const float4 q = fin4[(size_t)n * 64 + lane];
    float4 acc = q;  // feats + agg starts from feats

    const int d = deg[n];
    const int* cl = cols + (size_t)n * MAXD;

    int i = 0;
    for (; i + 2 <= d; i += 2) {
        const int m0 = cl[i];
        const int m1 = cl[i + 1];
        const float4 f0 = fin4[(size_t)m0 * 64 + lane];
        const float4 f1 = fin4[(size_t)m1 * 64 + lane];

        float p0 = fmaf(q.x, f0.x, fmaf(q.y, f0.y, fmaf(q.z, f0.z, q.w * f0.w)));
        float p1 = fmaf(q.x, f1.x, fmaf(q.y, f1.y, fmaf(q.z, f1.z, q.w * f1.w)));
        p0 += __shfl_xor(p0, 1, 64);  p1 += __shfl_xor(p1, 1, 64);
        p0 += __shfl_xor(p0, 2, 64);  p1 += __shfl_xor(p1, 2, 64);
        p0 += __shfl_xor(p0, 4, 64);  p1 += __shfl_xor(p1, 4, 64);
        p0 += __shfl_xor(p0, 8, 64);  p1 += __shfl_xor(p1, 8, 64);
        const float a1 = __shfl_xor(p0, 16, 64);
        const float b1 = __shfl_xor(p1, 16, 64);
        const float a2 = __shfl_xor(p0, 32, 64);
        const float b2 = __shfl_xor(p1, 32, 64);
        const float a3 = __shfl_xor(a1, 32, 64);
        const float b3 = __shfl_xor(b1, 32, 64);

        const float e0 = __expf(p0);
        const float g0 = __expf(p1);
        const float w0 = e0 / (e0 + __expf(a1) + __expf(a2) + __expf(a3));
        const float w1 = g0 / (g0 + __expf(b1) + __expf(b2) + __expf(b3));

        acc.x = fmaf(w0, f0.x, fmaf(w1, f1.x, acc.x));
        acc.y = fmaf(w0, f0.y, fmaf(w1, f1.y, acc.y));
        acc.z = fmaf(w0, f0.z, fmaf(w1, f1.z, acc.z));
        acc.w = fmaf(w0, f0.w, fmaf(w1, f1.w, acc.w));
    }
    if (i < d) {
        const int m = cl[i];
        const float4 f = fin4[(size_t)m * 64 + lane];
        float p = fmaf(q.x, f.x, fmaf(q.y, f.y, fmaf(q.z, f.z, q.w * f.w)));
        p += __shfl_xor(p, 1, 64);
        p += __shfl_xor(p, 2, 64);
        p += __shfl_xor(p, 4, 64);
        p += __shfl_xor(p, 8, 64);
        const float t1 = __shfl_xor(p, 16, 64);
        const float t2 = __shfl_xor(p, 32, 64);
        const float t3 = __shfl_xor(t1, 32, 64);
        const float e0 = __expf(p);
        const float w  = e0 / (e0 + __expf(t1) + __expf(t2) + __expf(t3));
        acc.x = fmaf(w, f.x, acc.x);
        acc.y = fmaf(w, f.y, acc.y);
        acc.z = fmaf(w, f.z, acc.z);
        acc.w = fmaf(w, f.w, acc.w);
    }

    // per-channel L2 norm: reduce |acc|^2 over the 16-lane channel group
    float ss = fmaf(acc.x, acc.x, fmaf(acc.y, acc.y, fmaf(acc.z, acc.z, acc.w * acc.w)));
    ss += __shfl_xor(ss, 1, 64);
    ss += __shfl_xor(ss, 2, 64);
    ss += __shfl_xor(ss, 4, 64);
    ss += __shfl_xor(ss, 8, 64);
    const float rn = 1.0f / fmaxf(sqrtf(ss), 1e-12f);
    acc.x *= rn; acc.y *= rn; acc.z *= rn; acc.w *= rn;

    ((float4*)fout)[(size_t)n * 64 + lane] = acc;
}

extern "C" void kernel_launch(void* const* d_in, const int* in_sizes, int n_in,
                              void* d_out, int out_size, void* d_ws, size_t ws_size,
                              hipStream_t stream) {
    const float* features = (const float*)d_in[0];   // [6144, 512]
    const int*   adj      = (const int*)d_in[1];     // [6144, 6144]
    const float* W        = (const float*)d_in[2];   // [4, 512, 64]
    const float* b        = (const float*)d_in[3];   // [4, 1, 64]
    float* out = (float*)d_out;                      // [6144, 256] == [n][c][k] flat

    float* featsA = (float*)d_ws;                    // N*NODE floats
    float* featsB = featsA + (size_t)NN * NODE;
    int*   deg    = (int*)(featsB + (size_t)NN * NODE);
    int*   cols   = deg + NN;                        // N*MAXD ints

    proj_kernel<<<NN / PR, 256, 0, stream>>>(features, W, b, featsA);
    ell_kernel<<<NN, 256, 0, stream>>>(adj, deg, cols);
    iter_kernel<<<NN, 64, 0, stream>>>(featsA, featsB, deg, cols);
    iter_kernel<<<NN, 64, 0, stream>>>(featsB, featsA, deg, cols);
    // final iteration writes d_out directly: [n][c][k] == [n][c*64+k]
    iter_kernel<<<NN, 64, 0, stream>>>(featsA, out, deg, cols);
}

// Round 5
// 319.847 us; speedup vs baseline: 1.5323x; 1.0668x over previous
//
#include <hip/hip_runtime.h>
#include <hip/hip_bf16.h>
#include <math.h>

#define NN      6144
#define IN_DIM  512
#define CH      4
#define CDIM    64
#define NODE    (CH * CDIM)      // 256 floats per node
#define PR      16               // rows per projection block
#define MAXD    96               // max degree slot (mean ~31, ~12 sigma margin)

typedef int  v4i __attribute__((ext_vector_type(4)));   // nontemporal-compatible int4

// ---------------------------------------------------------------------------
// Kernel 1: projection as register-blocked fp32 GEMM + bias + L2 norm.
// 256 threads/block; 16 feature rows staged in LDS once (32 KB). Thread
// (wave g, lane q) owns a 4x4 tile. Per K-step: 4 broadcast ds_read_b128 +
// 4 coalesced W dwordx4 + 64 v_fma -> FMA-issue-bound.
// Output layout: feats[n][c][k] (node-major 1 KB)
// ---------------------------------------------------------------------------
__global__ __launch_bounds__(256) void proj_kernel(
    const float* __restrict__ feat,   // [N, IN_DIM]
    const float* __restrict__ W,      // [CH, IN_DIM, CDIM]
    const float* __restrict__ bias,   // [CH, 1, CDIM]
    float* __restrict__ out)          // [N, CH, CDIM]
{
    __shared__ float lds[PR * IN_DIM];  // 32 KB
    const int t    = threadIdx.x;
    const int row0 = blockIdx.x * PR;

    {
        const float4* src = (const float4*)(feat + (size_t)row0 * IN_DIM);
        float4* dst = (float4*)lds;
#pragma unroll
        for (int i = 0; i < (PR * IN_DIM / 4) / 256; ++i)
            dst[t + i * 256] = src[t + i * 256];
    }
    __syncthreads();

    const int g  = t >> 6;        // wave = row sub-group (4 rows)
    const int q  = t & 63;        // col quad id
    const int c  = q >> 4;        // channel
    const int k0 = (q & 15) * 4;  // col offset within channel

    float acc[4][4];
#pragma unroll
    for (int r = 0; r < 4; ++r)
#pragma unroll
        for (int j = 0; j < 4; ++j) acc[r][j] = 0.0f;

    const float* Wc   = W + (size_t)c * IN_DIM * CDIM + k0;
    const float* arow = lds + g * 4 * IN_DIM;

    for (int d = 0; d < IN_DIM; d += 4) {
        const float4 w0 = *(const float4*)(Wc + (size_t)(d + 0) * CDIM);
        const float4 w1 = *(const float4*)(Wc + (size_t)(d + 1) * CDIM);
        const float4 w2 = *(const float4*)(Wc + (size_t)(d + 2) * CDIM);
        const float4 w3 = *(const float4*)(Wc + (size_t)(d + 3) * CDIM);
#pragma unroll
        for (int r = 0; r < 4; ++r) {
            const float4 a = *(const float4*)(arow + r * IN_DIM + d);  // uniform -> broadcast
            acc[r][0] = fmaf(a.x, w0.x, fmaf(a.y, w1.x, fmaf(a.z, w2.x, fmaf(a.w, w3.x, acc[r][0]))));
            acc[r][1] = fmaf(a.x, w0.y, fmaf(a.y, w1.y, fmaf(a.z, w2.y, fmaf(a.w, w3.y, acc[r][1]))));
            acc[r][2] = fmaf(a.x, w0.z, fmaf(a.y, w1.z, fmaf(a.z, w2.z, fmaf(a.w, w3.z, acc[r][2]))));
            acc[r][3] = fmaf(a.x, w0.w, fmaf(a.y, w1.w, fmaf(a.z, w2.w, fmaf(a.w, w3.w, acc[r][3]))));
        }
    }

    const float4 bv = *(const float4*)(bias + c * CDIM + k0);
#pragma unroll
    for (int r = 0; r < 4; ++r) {
        acc[r][0] += bv.x; acc[r][1] += bv.y; acc[r][2] += bv.z; acc[r][3] += bv.w;
    }

    // L2 norm per (row, channel): reduce over the 16 lanes of this channel
#pragma unroll
    for (int r = 0; r < 4; ++r) {
        float ss = acc[r][0] * acc[r][0] + acc[r][1] * acc[r][1]
                 + acc[r][2] * acc[r][2] + acc[r][3] * acc[r][3];
        ss += __shfl_xor(ss, 1, 64);
        ss += __shfl_xor(ss, 2, 64);
        ss += __shfl_xor(ss, 4, 64);
        ss += __shfl_xor(ss, 8, 64);
        const float rn = __builtin_amdgcn_rsqf(fmaxf(ss, 1e-24f));
        float4 res = make_float4(acc[r][0] * rn, acc[r][1] * rn, acc[r][2] * rn, acc[r][3] * rn);
        *(float4*)(out + (size_t)(row0 + g * 4 + r) * NODE + c * CDIM + k0) = res;
    }
}

// ---------------------------------------------------------------------------
// Kernel 2: dense adj row -> fixed-width neighbor list (ELL). One block/row.
// HBM-floor bound (151 MB stream); nontemporal loads (zero reuse).
// ---------------------------------------------------------------------------
__global__ __launch_bounds__(256) void ell_kernel(
    const int* __restrict__ adj,   // [N, N] 0/1
    int* __restrict__ deg,         // [N]
    int* __restrict__ cols)        // [N, MAXD]
{
    __shared__ int cnt;
    const int n = blockIdx.x;
    if (threadIdx.x == 0) cnt = 0;
    __syncthreads();

    const v4i* row = (const v4i*)(adj + (size_t)n * NN);
    int* rowcols = cols + (size_t)n * MAXD;
    for (int i = threadIdx.x; i < NN / 4; i += 256) {
        const v4i v = __builtin_nontemporal_load(&row[i]);
        if (v.x | v.y | v.z | v.w) {
            const int base = i * 4;
            if (v.x) { int p = atomicAdd(&cnt, 1); if (p < MAXD) rowcols[p] = base + 0; }
            if (v.y) { int p = atomicAdd(&cnt, 1); if (p < MAXD) rowcols[p] = base + 1; }
            if (v.z) { int p = atomicAdd(&cnt, 1); if (p < MAXD) rowcols[p] = base + 2; }
            if (v.w) { int p = atomicAdd(&cnt, 1); if (p < MAXD) rowcols[p] = base + 3; }
        }
    }
    __syncthreads();
    if (threadIdx.x == 0) deg[n] = min(cnt, MAXD);
}

// ---------------------------------------------------------------------------
// Kernel 3: one propagation iteration. 256-thread blocks, 4 rows (1/wave).
// Layout [n][c][k]: lane = c*16 + kq holds float4 of k = 4*kq..4*kq+3.
// Per neighbor: 1 gather, 4-step 16-lane butterfly dot, 1 exp (own channel
// only), 2-shuffle channel-sum, v_rcp softmax, 4 FMA. 6 DS ops/neighbor.
// Neighbor chunks of 4 (one s_load_dwordx4), double-buffered gathers.
// Scores are unit-vector dots in [-1,1] -> no max-shift needed.
// ---------------------------------------------------------------------------
__global__ __launch_bounds__(256) void iter_kernel(
    const float* __restrict__ fin,   // [N, CH, CDIM]
    float* __restrict__ fout,        // [N, CH, CDIM]
    const int* __restrict__ deg,
    const int* __restrict__ cols)
{
    const int wv   = threadIdx.x >> 6;
    const int lane = threadIdx.x & 63;
    const int n    = blockIdx.x * 4 + wv;

    const float4* fin4 = (const float4*)fin;
    const float4 q = fin4[(size_t)n * 64 + lane];
    float4 acc = q;  // feats + agg starts from feats

    const int d = deg[n];
    const int* cl = cols + (size_t)n * MAXD;
    const int nch = d >> 2;

    int4   mm;
    float4 f0, f1, f2, f3;
    if (nch > 0) {
        mm = *(const int4*)cl;                       // uniform -> s_load_dwordx4
        f0 = fin4[(size_t)mm.x * 64 + lane];
        f1 = fin4[(size_t)mm.y * 64 + lane];
        f2 = fin4[(size_t)mm.z * 64 + lane];
        f3 = fin4[(size_t)mm.w * 64 + lane];
    }

    for (int ch = 0; ch < nch; ++ch) {
        int4   mn;
        float4 g0, g1, g2, g3;
        const bool more = (ch + 1 < nch);
        if (more) {                                   // prefetch next chunk
            mn = *(const int4*)(cl + (ch + 1) * 4);
            g0 = fin4[(size_t)mn.x * 64 + lane];
            g1 = fin4[(size_t)mn.y * 64 + lane];
            g2 = fin4[(size_t)mn.z * 64 + lane];
            g3 = fin4[(size_t)mn.w * 64 + lane];
        }

        float p0 = fmaf(q.x, f0.x, fmaf(q.y, f0.y, fmaf(q.z, f0.z, q.w * f0.w)));
        float p1 = fmaf(q.x, f1.x, fmaf(q.y, f1.y, fmaf(q.z, f1.z, q.w * f1.w)));
        float p2 = fmaf(q.x, f2.x, fmaf(q.y, f2.y, fmaf(q.z, f2.z, q.w * f2.w)));
        float p3 = fmaf(q.x, f3.x, fmaf(q.y, f3.y, fmaf(q.z, f3.z, q.w * f3.w)));
#pragma unroll
        for (int off = 1; off <= 8; off <<= 1) {
            p0 += __shfl_xor(p0, off, 64);
            p1 += __shfl_xor(p1, off, 64);
            p2 += __shfl_xor(p2, off, 64);
            p3 += __shfl_xor(p3, off, 64);
        }
        // one exp per lane (its own channel's score)
        const float e0 = __expf(p0);
        const float e1 = __expf(p1);
        const float e2 = __expf(p2);
        const float e3 = __expf(p3);
        // channel-sum via 2 shuffles
        float s0 = e0 + __shfl_xor(e0, 16, 64);
        float s1 = e1 + __shfl_xor(e1, 16, 64);
        float s2 = e2 + __shfl_xor(e2, 16, 64);
        float s3 = e3 + __shfl_xor(e3, 16, 64);
        s0 += __shfl_xor(s0, 32, 64);
        s1 += __shfl_xor(s1, 32, 64);
        s2 += __shfl_xor(s2, 32, 64);
        s3 += __shfl_xor(s3, 32, 64);
        const float w0 = e0 * __builtin_amdgcn_rcpf(s0);
        const float w1 = e1 * __builtin_amdgcn_rcpf(s1);
        const float w2 = e2 * __builtin_amdgcn_rcpf(s2);
        const float w3 = e3 * __builtin_amdgcn_rcpf(s3);

        acc.x = fmaf(w0, f0.x, fmaf(w1, f1.x, fmaf(w2, f2.x, fmaf(w3, f3.x, acc.x))));
        acc.y = fmaf(w0, f0.y, fmaf(w1, f1.y, fmaf(w2, f2.y, fmaf(w3, f3.y, acc.y))));
        acc.z = fmaf(w0, f0.z, fmaf(w1, f1.z, fmaf(w2, f2.z, fmaf(w3, f3.z, acc.z))));
        acc.w = fmaf(w0, f0.w, fmaf(w1, f1.w, fmaf(w2, f2.w, fmaf(w3, f3.w, acc.w))));

        if (more) { f0 = g0; f1 = g1; f2 = g2; f3 = g3; }
    }

    // tail
    for (int i = nch * 4; i < d; ++i) {
        const int m = cl[i];
        const float4 f = fin4[(size_t)m * 64 + lane];
        float p = fmaf(q.x, f.x, fmaf(q.y, f.y, fmaf(q.z, f.z, q.w * f.w)));
        p += __shfl_xor(p, 1, 64);
        p += __shfl_xor(p, 2, 64);
        p += __shfl_xor(p, 4, 64);
        p += __shfl_xor(p, 8, 64);
        const float e = __expf(p);
        float s = e + __shfl_xor(e, 16, 64);
        s += __shfl_xor(s, 32, 64);
        const float w = e * __builtin_amdgcn_rcpf(s);
        acc.x = fmaf(w, f.x, acc.x);
        acc.y = fmaf(w, f.y, acc.y);
        acc.z = fmaf(w, f.z, acc.z);
        acc.w = fmaf(w, f.w, acc.w);
    }

    // per-channel L2 norm over the 16-lane channel group
    float ss = fmaf(acc.x, acc.x, fmaf(acc.y, acc.y, fmaf(acc.z, acc.z, acc.w * acc.w)));
    ss += __shfl_xor(ss, 1, 64);
    ss += __shfl_xor(ss, 2, 64);
    ss += __shfl_xor(ss, 4, 64);
    ss += __shfl_xor(ss, 8, 64);
    const float rn = __builtin_amdgcn_rsqf(fmaxf(ss, 1e-24f));
    acc.x *= rn; acc.y *= rn; acc.z *= rn; acc.w *= rn;

    ((float4*)fout)[(size_t)n * 64 + lane] = acc;
}

extern "C" void kernel_launch(void* const* d_in, const int* in_sizes, int n_in,
                              void* d_out, int out_size, void* d_ws, size_t ws_size,
                              hipStream_t stream) {
    const float* features = (const float*)d_in[0];   // [6144, 512]
    const int*   adj      = (const int*)d_in[1];     // [6144, 6144]
    const float* W        = (const float*)d_in[2];   // [4, 512, 64]
    const float* b        = (const float*)d_in[3];   // [4, 1, 64]
    float* out = (float*)d_out;                      // [6144, 256] == [n][c][k] flat

    float* featsA = (float*)d_ws;                    // N*NODE floats
    float* featsB = featsA + (size_t)NN * NODE;
    int*   deg    = (int*)(featsB + (size_t)NN * NODE);
    int*   cols   = deg + NN;                        // N*MAXD ints

    proj_kernel<<<NN / PR, 256, 0, stream>>>(features, W, b, featsA);
    ell_kernel<<<NN, 256, 0, stream>>>(adj, deg, cols);
    iter_kernel<<<NN / 4, 256, 0, stream>>>(featsA, featsB, deg, cols);
    iter_kernel<<<NN / 4, 256, 0, stream>>>(featsB, featsA, deg, cols);
    // final iteration writes d_out directly: [n][c][k] == [n][c*64+k]
    iter_kernel<<<NN / 4, 256, 0, stream>>>(featsA, out, deg, cols);
}